// Round 1
// baseline (304.564 us; speedup 1.0000x reference)
//
#include <hip/hip_runtime.h>
#include <stdint.h>

// Problem: B=2, S=2048, D_MODEL=1024, H=16, Hd=64.
// out = softmax((xWq^T)(xWk^T)^T / 8) (xWv^T), per (b,h).
//
// Stage 1: cvt fp32 -> bf16 (x, Wq, Wk, Wv)
// Stage 2: QKV GEMM (m97 structure: 128x128 tile, BK=32, global_load_lds x16,
//          mfma_f32_16x16x32_bf16, 4 waves x 4x4 tiles)
// Stage 3: flash attention, 64 q-rows/block, 32 keys/iter, online softmax.

typedef __bf16 bf16x8 __attribute__((ext_vector_type(8)));
typedef __bf16 bf16x4 __attribute__((ext_vector_type(4)));
typedef float  f32x4  __attribute__((ext_vector_type(4)));

#define D_MODEL 1024
#define SEQ     2048
#define NHEAD   16
#define HDIM    64

__device__ __forceinline__ void load_lds16(const void* g, void* lds) {
  __builtin_amdgcn_global_load_lds(
      (__attribute__((address_space(1))) void*)(uintptr_t)g,
      (__attribute__((address_space(3))) void*)(uintptr_t)lds,
      16, 0, 0);
}

// ---------------- Stage 1: fp32 -> bf16 ----------------
__global__ void cvt_f32_bf16(const float* __restrict__ in,
                             __bf16* __restrict__ out, int n4) {
  int i = blockIdx.x * blockDim.x + threadIdx.x;
  if (i < n4) {
    float4 v = ((const float4*)in)[i];
    bf16x4 o;
    o[0] = (__bf16)v.x; o[1] = (__bf16)v.y;
    o[2] = (__bf16)v.z; o[3] = (__bf16)v.w;
    ((bf16x4*)out)[i] = o;
  }
}

// ---------------- Stage 2: QKV projection GEMM ----------------
// C[m,n] = sum_k X[m,k] * W[n,k];  M=4096, N=1024, K=1024. Output bf16.
__global__ __launch_bounds__(256) void qkv_gemm(
    const __bf16* __restrict__ X,
    const __bf16* __restrict__ Wq, const __bf16* __restrict__ Wk,
    const __bf16* __restrict__ Wv,
    __bf16* __restrict__ Qb, __bf16* __restrict__ Kb, __bf16* __restrict__ Vb) {
  __shared__ __bf16 As[128 * 32];
  __shared__ __bf16 Bs[128 * 32];

  const __bf16* W  = (blockIdx.z == 0) ? Wq : (blockIdx.z == 1) ? Wk : Wv;
  __bf16*       Out = (blockIdx.z == 0) ? Qb : (blockIdx.z == 1) ? Kb : Vb;

  const int t    = threadIdx.x;
  const int wv   = t >> 6;
  const int lane = t & 63;
  const int l15  = lane & 15;
  const int quad = lane >> 4;
  const int m0   = blockIdx.y * 128;
  const int n0   = blockIdx.x * 128;
  const int wm   = (wv >> 1) * 64;   // wave's m offset in tile
  const int wn   = (wv & 1) * 64;    // wave's n offset in tile

  f32x4 acc[4][4] = {};

  for (int it = 0; it < 32; ++it) {
    const int k0 = it * 32;
    // stage 128x32 A-tile and B-tile: 512 16B-chunks each, 2 per thread
#pragma unroll
    for (int p = 0; p < 2; ++p) {
      const int c   = p * 256 + t;          // chunk id
      const int row = c >> 2;               // tile row
      const int ko  = (c & 3) * 8;          // k offset (elements)
      const unsigned lb = (unsigned)((p * 256 + wv * 64) * 16);  // wave-uniform lds byte base
      load_lds16(X + (size_t)(m0 + row) * D_MODEL + k0 + ko, (char*)As + lb);
      load_lds16(W + (size_t)(n0 + row) * D_MODEL + k0 + ko, (char*)Bs + lb);
    }
    __syncthreads();

    bf16x8 af[4], bfb[4];
#pragma unroll
    for (int i = 0; i < 4; ++i)
      af[i] = *(const bf16x8*)&As[(wm + i * 16 + l15) * 32 + quad * 8];
#pragma unroll
    for (int j = 0; j < 4; ++j)
      bfb[j] = *(const bf16x8*)&Bs[(wn + j * 16 + l15) * 32 + quad * 8];
#pragma unroll
    for (int i = 0; i < 4; ++i)
#pragma unroll
      for (int j = 0; j < 4; ++j)
        acc[i][j] = __builtin_amdgcn_mfma_f32_16x16x32_bf16(af[i], bfb[j],
                                                            acc[i][j], 0, 0, 0);
    __syncthreads();
  }

  // epilogue: C/D layout col=lane&15, row=quad*4+reg
#pragma unroll
  for (int i = 0; i < 4; ++i) {
    const int rg = m0 + wm + i * 16 + quad * 4;
#pragma unroll
    for (int j = 0; j < 4; ++j) {
      const int cg = n0 + wn + j * 16 + l15;
#pragma unroll
      for (int r = 0; r < 4; ++r)
        Out[(size_t)(rg + r) * D_MODEL + cg] = (__bf16)acc[i][j][r];
    }
  }
}

// ---------------- Stage 3: flash attention ----------------
// grid (S/64, H, B), block 256. Wave handles 16 q rows; 32 keys per iteration.
__global__ __launch_bounds__(256) void attn(
    const __bf16* __restrict__ Qb, const __bf16* __restrict__ Kb,
    const __bf16* __restrict__ Vb, float* __restrict__ out) {
  __shared__ float Ps[4][16][40];  // per-wave P transpose buffer

  const int t    = threadIdx.x;
  const int wv   = t >> 6;
  const int lane = t & 63;
  const int l15  = lane & 15;
  const int quad = lane >> 4;
  const int h    = blockIdx.y;
  const size_t bo = (size_t)blockIdx.z * SEQ;   // batch row offset
  const int q0   = blockIdx.x * 64 + wv * 16;
  const int hd0  = h * HDIM;

  // Q fragments (A-operand, pre-scaled by 1/sqrt(64)=0.125, exact in bf16)
  bf16x8 qf[2];
#pragma unroll
  for (int c = 0; c < 2; ++c) {
    qf[c] = *(const bf16x8*)&Qb[(bo + q0 + l15) * D_MODEL + hd0 + c * 32 + quad * 8];
#pragma unroll
    for (int j = 0; j < 8; ++j)
      qf[c][j] = (__bf16)(0.125f * (float)qf[c][j]);
  }

  float m_i[4], l_i[4];
  f32x4 o_acc[4] = {};
#pragma unroll
  for (int r = 0; r < 4; ++r) { m_i[r] = -1e30f; l_i[r] = 0.f; }

  const __bf16* Krow = Kb + (bo + l15) * D_MODEL + hd0 + quad * 8;
  const __bf16* Vrow = Vb + (bo + quad * 8) * D_MODEL + hd0 + l15;

  for (int kt = 0; kt < 64; ++kt) {
    const int n0 = kt * 32;
    // scores: two 16-key tiles
    f32x4 s0 = {}, s1 = {};
    {
      bf16x8 kf0 = *(const bf16x8*)&Krow[(size_t)(n0) * D_MODEL];
      bf16x8 kf1 = *(const bf16x8*)&Krow[(size_t)(n0) * D_MODEL + 32];
      s0 = __builtin_amdgcn_mfma_f32_16x16x32_bf16(qf[0], kf0, s0, 0, 0, 0);
      s0 = __builtin_amdgcn_mfma_f32_16x16x32_bf16(qf[1], kf1, s0, 0, 0, 0);
      bf16x8 kf2 = *(const bf16x8*)&Krow[(size_t)(n0 + 16) * D_MODEL];
      bf16x8 kf3 = *(const bf16x8*)&Krow[(size_t)(n0 + 16) * D_MODEL + 32];
      s1 = __builtin_amdgcn_mfma_f32_16x16x32_bf16(qf[0], kf2, s1, 0, 0, 0);
      s1 = __builtin_amdgcn_mfma_f32_16x16x32_bf16(qf[1], kf3, s1, 0, 0, 0);
    }

    // online softmax per q-row (row = quad*4 + r, cols spread over 16 lanes)
    float p0[4], p1[4], alpha[4];
#pragma unroll
    for (int r = 0; r < 4; ++r) {
      float a = s0[r], b = s1[r];
      float rm = fmaxf(a, b);
      rm = fmaxf(rm, __shfl_xor(rm, 1));
      rm = fmaxf(rm, __shfl_xor(rm, 2));
      rm = fmaxf(rm, __shfl_xor(rm, 4));
      rm = fmaxf(rm, __shfl_xor(rm, 8));
      float mn = fmaxf(m_i[r], rm);
      p0[r] = __expf(a - mn);
      p1[r] = __expf(b - mn);
      float rs = p0[r] + p1[r];
      rs += __shfl_xor(rs, 1);
      rs += __shfl_xor(rs, 2);
      rs += __shfl_xor(rs, 4);
      rs += __shfl_xor(rs, 8);
      alpha[r] = __expf(m_i[r] - mn);
      l_i[r]   = l_i[r] * alpha[r] + rs;
      m_i[r]   = mn;
    }
#pragma unroll
    for (int tt = 0; tt < 4; ++tt)
#pragma unroll
      for (int r = 0; r < 4; ++r) o_acc[tt][r] *= alpha[r];

    // P: C-layout -> A-layout via per-wave LDS (same-wave DS ops are in-order)
#pragma unroll
    for (int r = 0; r < 4; ++r) {
      Ps[wv][quad * 4 + r][l15]      = p0[r];
      Ps[wv][quad * 4 + r][16 + l15] = p1[r];
    }
    bf16x8 pf;
#pragma unroll
    for (int j = 0; j < 8; ++j)
      pf[j] = (__bf16)Ps[wv][l15][quad * 8 + j];

    // PV: V as B-operand, 4 d-tiles
#pragma unroll
    for (int tt = 0; tt < 4; ++tt) {
      bf16x8 vf;
#pragma unroll
      for (int j = 0; j < 8; ++j)
        vf[j] = Vrow[(size_t)(n0 + j) * D_MODEL + tt * 16];
      o_acc[tt] = __builtin_amdgcn_mfma_f32_16x16x32_bf16(pf, vf, o_acc[tt], 0, 0, 0);
    }
  }

  // epilogue: out[b, q, h*64 + d] fp32
#pragma unroll
  for (int r = 0; r < 4; ++r) {
    float inv = 1.f / l_i[r];
    const size_t row = bo + q0 + quad * 4 + r;
#pragma unroll
    for (int tt = 0; tt < 4; ++tt)
      out[row * D_MODEL + hd0 + tt * 16 + l15] = o_acc[tt][r] * inv;
  }
}

extern "C" void kernel_launch(void* const* d_in, const int* in_sizes, int n_in,
                              void* d_out, int out_size, void* d_ws, size_t ws_size,
                              hipStream_t stream) {
  const float* x  = (const float*)d_in[0];
  const float* Wq = (const float*)d_in[1];
  const float* Wk = (const float*)d_in[2];
  const float* Wv = (const float*)d_in[3];
  float* out = (float*)d_out;

  char* ws = (char*)d_ws;
  __bf16* xb  = (__bf16*)(ws);                       //  8 MB (4096x1024)
  __bf16* wqb = (__bf16*)(ws + (8u  << 20));         //  2 MB
  __bf16* wkb = (__bf16*)(ws + (10u << 20));         //  2 MB
  __bf16* wvb = (__bf16*)(ws + (12u << 20));         //  2 MB
  __bf16* Qbf = (__bf16*)(ws + (14u << 20));         //  8 MB
  __bf16* Kbf = (__bf16*)(ws + (22u << 20));         //  8 MB
  __bf16* Vbf = (__bf16*)(ws + (30u << 20));         //  8 MB  (total 38 MB)

  cvt_f32_bf16<<<4096, 256, 0, stream>>>(x,  xb,  4194304 / 4);
  cvt_f32_bf16<<<1024, 256, 0, stream>>>(Wq, wqb, 1048576 / 4);
  cvt_f32_bf16<<<1024, 256, 0, stream>>>(Wk, wkb, 1048576 / 4);
  cvt_f32_bf16<<<1024, 256, 0, stream>>>(Wv, wvb, 1048576 / 4);

  qkv_gemm<<<dim3(8, 32, 3), 256, 0, stream>>>(xb, wqb, wkb, wvb, Qbf, Kbf, Vbf);

  attn<<<dim3(SEQ / 64, NHEAD, 2), 256, 0, stream>>>(Qbf, Kbf, Vbf, out);
}